// Round 16
// baseline (27083.337 us; speedup 1.0000x reference)
//
#include <hip/hip_runtime.h>
#include <hip/hip_fp16.h>

#define T_STEPS 4096
#define RES     4096
#define NIN     64
#define NOUT    32
#define NWG     256
#define TPB     512            // 8 waves; wave wv owns cols [512wv,512wv+512)
#define WQS     1028           // u32 stride per W row in LDS (4112 B: bank-tiled b128)

typedef unsigned long long ull;
typedef int i32x4 __attribute__((ext_vector_type(4)));

// any zero byte in q? (encoded bytes are always in [1,255])
__device__ __forceinline__ bool haszero(ull q) {
    return ((q - 0x0101010101010101ull) & ~q & 0x8080808080808080ull) != 0ull;
}

// U = inputs @ W_in^T as fp16. Block: 16 t x 256 j. Grid (16, 256). (proven r12+)
__global__ __launch_bounds__(256)
void esn_uproj(const float* __restrict__ inp, const float* __restrict__ Win,
               __half* __restrict__ Uh)
{
    __shared__ float us[16][NIN];
    const int tid = threadIdx.x;
    const int j   = blockIdx.x * 256 + tid;
    const int t0  = blockIdx.y * 16;
    ((float4*)us)[tid] = ((const float4*)(inp + (size_t)t0 * NIN))[tid];
    float wr[NIN];
    const float4* wp = (const float4*)(Win + (size_t)j * NIN);
#pragma unroll
    for (int k = 0; k < 16; ++k) {
        float4 v = wp[k];
        wr[4*k] = v.x; wr[4*k+1] = v.y; wr[4*k+2] = v.z; wr[4*k+3] = v.w;
    }
    __syncthreads();
#pragma unroll
    for (int tt = 0; tt < 16; ++tt) {
        float s = 0.f;
#pragma unroll
        for (int k = 0; k < NIN; ++k) s += wr[k] * us[tt][k];
        Uh[(size_t)(t0 + tt) * RES + j] = __float2half_rn(s);
    }
}

// ---------------------------------------------------------------------------
// Persistent recurrence, INT8 MFMA edition (r8 structure, half the LDS ops).
// 256 WGs x 512 thr; WG g owns rows 16g..16g+15; wave wv owns cols [512wv,+512).
//
// r15 lesson: intra-wave poll/compute "overlap" is a SIMT fallacy. Keep r8's
// wave-granular flow; cut the LDS op count instead:
//   W quantized int8 per-row (scale 127/rowmax, computed here) -> LDS 64 KB,
//   8 ds_read_b128/lane/step. x exchanged as int8 (byte = xq+128, never 0;
//   decode = XOR 0x80) -> poll is ONE 8-B load/lane; B frags 8 reads.
//   8 x v_mfma_i32_16x16x64_i8, i32 exact accum; dequant once at the reduce
//   (x dq[row] = rowmax/127^2), add U[t], tanh, publish 2 B/wave.
// A/B both packed with the same (lane>>4, byte)->k map -> any HW k-permutation
// cancels (validated r9 for f16; same ISA structure). C layout dtype-indep.
// Wq rows stride 4112 B: consecutive-8 lanes' b128 reads tile all 32 banks.
// W staging LAUNDERED (r12). Sync/publish/red: r8 verbatim (proven).
// ---------------------------------------------------------------------------
__global__ __launch_bounds__(TPB, 1)
void esn_recur(const __half* __restrict__ Uh,
               const float* __restrict__ W,
               unsigned char* __restrict__ Xb)   // [T][RES] int8 encoded (+128)
{
    __shared__ unsigned int Wq[16 * WQS];             // 65.8 KB int8 W tile
    __shared__ __align__(16) unsigned char xh[RES];   // 4 KB decoded slices
    __shared__ float mx[16][32];                      // rowmax partials / srow
    __shared__ float dq[16];                          // dequant per row
    __shared__ int   red[2][16][9];                   // partials, parity dbuf

    const int g    = blockIdx.x;
    const int tid  = threadIdx.x;
    const int wv   = tid >> 6;
    const int lane = tid & 63;
    const int q    = lane >> 4;      // k-subgroup 0..3 (16 bytes each)
    const int r    = lane & 15;      // A row within the 16-row tile

    // ---- pass 1: per-row max|W| ----------------------------------------
    {
        const int row = tid >> 5, seg = tid & 31;     // 16 rows x 32 segs
        const float4* wr = (const float4*)(W + (size_t)(16 * g + row) * RES) + seg * 32;
        float m = 1e-30f;
#pragma unroll 4
        for (int i = 0; i < 32; ++i) {
            float4 v = wr[i];
            m = fmaxf(m, fmaxf(fmaxf(fabsf(v.x), fabsf(v.y)),
                               fmaxf(fabsf(v.z), fabsf(v.w))));
        }
        mx[row][seg] = m;
    }
    __syncthreads();
    if (tid < 16) {
        float m = 1e-30f;
#pragma unroll
        for (int s = 0; s < 32; ++s) m = fmaxf(m, mx[tid][s]);
        dq[tid]    = m / (127.0f * 127.0f);
        mx[tid][0] = 127.0f / m;                      // srow
    }
    __syncthreads();

    // ---- pass 2: quantize W -> int8 LDS (laundered, bank-tiled stride) --
    {
        for (int idx = tid; idx < 16 * 1024; idx += TPB) {
            int row = idx >> 10, c4 = idx & 1023;
            float s  = mx[row][0];
            float4 v = ((const float4*)(W + (size_t)(16 * g + row) * RES))[c4];
            int a0 = __float2int_rn(v.x * s), a1 = __float2int_rn(v.y * s);
            int a2 = __float2int_rn(v.z * s), a3 = __float2int_rn(v.w * s);
            unsigned pk = (a0 & 0xff) | ((a1 & 0xff) << 8) |
                          ((a2 & 0xff) << 16) | ((a3 & 0xff) << 24);
            asm volatile("" : "+v"(pk));              // no pure provenance
            Wq[row * WQS + c4] = pk;
        }
    }
    __syncthreads();                                  // tile + scales ready

    const float dqA = dq[2 * wv], dqB = dq[2 * wv + 1];
    const i32x4* WA = (const i32x4*)Wq;               // frag: 257r+32wv+4m+q
    const i32x4* XA = (const i32x4*)(xh + 512 * wv);  // frag: 4m+q

    for (int t = 1; t < T_STEPS; ++t) {
        // ---- prefetch U[t] (4 B uniform) + W frags (LDS idle during poll) -
        const __half2 u2 = *(const __half2*)(Uh + (size_t)t * RES + 16 * g + 2 * wv);
        i32x4 wf[8];
#pragma unroll
        for (int m = 0; m < 8; ++m)
            wf[m] = WA[257 * r + 32 * wv + 4 * m + q];

        // ---- poll my 8 B of x[t-1] (data-as-flag, one load) ---------------
        const ull* src = (const ull*)(Xb + (size_t)(t - 1) * RES) + 64 * wv + lane;
        ull qv;
        do {
            qv = __hip_atomic_load(src, __ATOMIC_RELAXED, __HIP_MEMORY_SCOPE_AGENT);
        } while (haszero(qv));
        qv ^= 0x8080808080808080ull;                  // decode to signed int8

        // ---- stage decoded 8 B (wave-private) -----------------------------
        ((ull*)(xh + 512 * wv))[lane] = qv;
        asm volatile("s_waitcnt lgkmcnt(0)" ::: "memory");

        // ---- 8 x mfma_i32_16x16x64_i8: rows 0..15, k = [512wv,+512) -------
        i32x4 acc = {0, 0, 0, 0};
#pragma unroll
        for (int m = 0; m < 8; ++m) {
            i32x4 b = XA[4 * m + q];
            acc = __builtin_amdgcn_mfma_i32_16x16x64_i8(wf[m], b, acc, 0, 0, 0);
        }

        // ---- C col 0 lanes publish partials (rows 4q..4q+3) ---------------
        if ((lane & 15) == 0) {
#pragma unroll
            for (int i = 0; i < 4; ++i)
                red[t & 1][4 * q + i][wv] = acc[i];
        }
        __syncthreads();                     // the ONE barrier per step

        // ---- wave wv reduces rows 2wv, 2wv+1; dequant+u+tanh; publish -----
        {
            const int row = 2 * wv + ((lane >> 3) & 1);
            int s = red[t & 1][row][lane & 7];
            s += __shfl_xor(s, 1, 64);
            s += __shfl_xor(s, 2, 64);
            s += __shfl_xor(s, 4, 64);       // lanes 0,8: row sums
            int s2 = __shfl_xor(s, 8, 64);   // lane 0 <- row 2wv+1 sum
            if (lane == 0) {
                float2 uf = __half22float2(u2);
                float x0 = tanhf((float)s  * dqA + uf.x);
                float x1 = tanhf((float)s2 * dqB + uf.y);
                int e0 = __float2int_rn(x0 * 127.0f) + 128;   // [1,255]
                int e1 = __float2int_rn(x1 * 127.0f) + 128;
                unsigned short pk = (unsigned short)((e0 & 0xff) | ((e1 & 0xff) << 8));
                __hip_atomic_store((unsigned short*)(Xb + (size_t)t * RES + 16 * g + 2 * wv),
                                   pk, __ATOMIC_RELAXED, __HIP_MEMORY_SCOPE_AGENT);
            }
        }
    }
}

// ---------------------------------------------------------------------------
// Readout: out[T,32] = decode(Xb) @ W_out. 2 t-rows/block.
// ---------------------------------------------------------------------------
__global__ __launch_bounds__(256)
void esn_out(const unsigned char* __restrict__ Xb,
             const float* __restrict__ Wout,
             float* __restrict__ out)
{
    __shared__ float xs[2 * RES];
    __shared__ float red[2][8][32];
    const int tid = threadIdx.x;
    const int t0  = blockIdx.x * 2;

    const ull* s8 = (const ull*)(Xb + (size_t)t0 * RES);
    for (int i = tid; i < 2 * RES / 8; i += 256) {
        ull v = s8[i];
        float* d = &xs[8 * i];
#pragma unroll
        for (int j = 0; j < 8; ++j) {
            int b = (int)((v >> (8 * j)) & 0xff) - 128;
            d[j] = (float)b * (1.0f / 127.0f);
        }
    }
    __syncthreads();

    const int o  = tid & 31;
    const int sg = tid >> 5;
    float acc0 = 0.f, acc1 = 0.f;
    const int rbeg = sg * 512;
    for (int rr = rbeg; rr < rbeg + 512; ++rr) {
        float wv = Wout[(size_t)rr * NOUT + o];
        acc0 += xs[rr] * wv;
        acc1 += xs[RES + rr] * wv;
    }
    red[0][sg][o] = acc0;
    red[1][sg][o] = acc1;
    __syncthreads();

    if (tid < 64) {
        const int h = tid >> 5, oo = tid & 31;
        float s = 0.f;
#pragma unroll
        for (int k = 0; k < 8; ++k) s += red[h][k][oo];
        out[(size_t)(t0 + h) * NOUT + oo] = s;
    }
}

// ---------------------------------------------------------------------------
extern "C" void kernel_launch(void* const* d_in, const int* in_sizes, int n_in,
                              void* d_out, int out_size, void* d_ws, size_t ws_size,
                              hipStream_t stream)
{
    const float* inputs = (const float*)d_in[0];   // [T, 64]
    const float* W_in   = (const float*)d_in[1];   // [RES, 64]
    const float* W      = (const float*)d_in[2];   // [RES, RES]
    const float* W_out  = (const float*)d_in[3];   // [RES, 32]
    float* out = (float*)d_out;                    // [T, 32]

    unsigned char* Xb = (unsigned char*)d_ws;                       // 16 MiB
    __half* Uh = (__half*)((char*)d_ws + (size_t)T_STEPS * RES);    // 32 MiB

    // Replay-safe: zero history (0x00 = "not written"), encode row 0
    // (x[0]=0 -> byte 0x80 everywhere in row 0).
    hipMemsetAsync(Xb, 0, (size_t)T_STEPS * RES, stream);
    hipMemsetAsync(Xb, 0x80, RES, stream);
    esn_uproj<<<dim3(RES / 256, T_STEPS / 16), dim3(256), 0, stream>>>(inputs, W_in, Uh);

    esn_recur<<<dim3(NWG), dim3(TPB), 0, stream>>>(Uh, W, Xb);
    esn_out<<<dim3(T_STEPS / 2), dim3(256), 0, stream>>>(Xb, W_out, out);
}